// Round 1
// baseline (676.436 us; speedup 1.0000x reference)
//
#include <hip/hip_runtime.h>

// SkeletalConv: grouped Conv1d over skeleton edges, fused neighbor-mean.
// x: (16, 25, 65536) f32, W: (48, 16, 16, 3) f32, b: (48, 16) f32
// out: (16, 24, 65533) f32, out[co,e,t] = 0.5*sum_{j,ci,k} W[2e+j,co,ci,k]*x[ci,e+j,t+k] + 0.5*(b[2e,co]+b[2e+1,co])

#define CIN   16
#define NJ    25
#define LSEQ  65536
#define NE    24
#define NCO   16
#define KW    3
#define LOUTN (LSEQ - KW + 1)   // 65533
#define TPT   4                 // t-outputs per thread
#define BLOCK 256
#define CHUNK (BLOCK * TPT)     // 1024
#define NCHUNK ((LOUTN + CHUNK - 1) / CHUNK)  // 64

__global__ __launch_bounds__(BLOCK, 4)
void skel_conv_kernel(const float* __restrict__ x,
                      const float* __restrict__ W,
                      const float* __restrict__ b,
                      float* __restrict__ out)
{
    // weights repacked: wlds[j][ci][co][4] (k in 0..2, pad at 3), 0.5 folded in
    __shared__ __align__(16) float wlds[2 * 16 * 16 * 4];
    __shared__ float blds[NCO];

    const int e   = blockIdx.y;
    const int tid = threadIdx.x;

    // ---- stage + repack this edge's weights into LDS (0.5 folded) ----
    const float* Wg = W + (size_t)(2 * e) * (NCO * CIN * KW);  // 1536 contiguous floats
    #pragma unroll
    for (int it = 0; it < 6; ++it) {
        int f  = tid + it * BLOCK;            // 0..1535
        int j  = f / 768;  int r  = f - j * 768;
        int co = r / 48;   int r2 = r - co * 48;
        int ci = r2 / 3;   int k  = r2 - ci * 3;
        wlds[((j * 16 + ci) * 16 + co) * 4 + k] = 0.5f * Wg[f];
    }
    if (tid < NCO)
        blds[tid] = 0.5f * (b[(2 * e) * NCO + tid] + b[(2 * e + 1) * NCO + tid]);
    __syncthreads();

    const int tbase = blockIdx.x * CHUNK + tid;

    // clamped load offsets (avoid OOB reads on the tail chunk; stores guarded)
    int off[TPT];
    bool valid[TPT];
    #pragma unroll
    for (int tt = 0; tt < TPT; ++tt) {
        int t = tbase + tt * BLOCK;
        valid[tt] = (t < LOUTN);
        off[tt]   = valid[tt] ? t : 0;
    }

    float acc[NCO][TPT];
    #pragma unroll
    for (int co = 0; co < NCO; ++co)
        #pragma unroll
        for (int tt = 0; tt < TPT; ++tt)
            acc[co][tt] = blds[co];

    const float4* wv = reinterpret_cast<const float4*>(wlds);

    #pragma unroll 1
    for (int ci = 0; ci < CIN; ++ci) {
        #pragma unroll
        for (int j = 0; j < 2; ++j) {
            const float* xp = x + (size_t)(ci * NJ + e + j) * LSEQ;
            float a0[TPT], a1[TPT], a2[TPT];
            #pragma unroll
            for (int tt = 0; tt < TPT; ++tt) {
                a0[tt] = xp[off[tt]];
                a1[tt] = xp[off[tt] + 1];
                a2[tt] = xp[off[tt] + 2];
            }
            #pragma unroll
            for (int co = 0; co < NCO; ++co) {
                float4 w = wv[(j * 16 + ci) * 16 + co];  // uniform -> LDS broadcast
                #pragma unroll
                for (int tt = 0; tt < TPT; ++tt) {
                    acc[co][tt] = fmaf(w.x, a0[tt], acc[co][tt]);
                    acc[co][tt] = fmaf(w.y, a1[tt], acc[co][tt]);
                    acc[co][tt] = fmaf(w.z, a2[tt], acc[co][tt]);
                }
            }
        }
    }

    // ---- store: out[co, e, t], coalesced dword stores ----
    #pragma unroll
    for (int co = 0; co < NCO; ++co) {
        float* op = out + (size_t)(co * NE + e) * LOUTN;
        #pragma unroll
        for (int tt = 0; tt < TPT; ++tt)
            if (valid[tt]) op[tbase + tt * BLOCK] = acc[co][tt];
    }
}

extern "C" void kernel_launch(void* const* d_in, const int* in_sizes, int n_in,
                              void* d_out, int out_size, void* d_ws, size_t ws_size,
                              hipStream_t stream)
{
    const float* x = (const float*)d_in[0];
    const float* W = (const float*)d_in[1];
    const float* b = (const float*)d_in[2];
    float* out     = (float*)d_out;

    dim3 grid(NCHUNK, NE);
    skel_conv_kernel<<<grid, BLOCK, 0, stream>>>(x, W, b, out);
}

// Round 2
// 85.033 us; speedup vs baseline: 7.9550x; 7.9550x over previous
//
#include <hip/hip_runtime.h>

// SkeletalConv: grouped Conv1d over skeleton edges, fused neighbor-mean.
// x: (16, 25, 65536) f32, W: (48, 16, 16, 3) f32, b: (48, 16) f32
// out: (16, 24, 65533) f32
// out[co,e,t] = 0.5*sum_{j,ci,k} W[2e+j,co,ci,k]*x[ci,e+j,t+k] + 0.5*(b[2e,co]+b[2e+1,co])

#define CIN   16
#define NJ    25
#define LSEQ  65536
#define NE    24
#define NCO   16
#define KW    3
#define LOUTN (LSEQ - KW + 1)   // 65533
#define COPT  8                 // co per thread (block split into 2 co-halves)
#define TPT   4                 // consecutive t per thread
#define BLOCK 256
#define TGRP  128               // threads per co-half
#define CHUNK (TGRP * TPT)      // 512 t per block
#define NCHUNK ((LOUTN + CHUNK - 1) / CHUNK)  // 128

__global__ __launch_bounds__(BLOCK)
void skel_conv_kernel(const float* __restrict__ x,
                      const float* __restrict__ W,
                      const float* __restrict__ b,
                      float* __restrict__ out)
{
    // weights repacked: wlds[j][ci][co][4] (k in 0..2, pad at 3), 0.5 folded in
    __shared__ __align__(16) float wlds[2 * 16 * 16 * 4];
    __shared__ float blds[NCO];

    const int e   = blockIdx.y;
    const int tid = threadIdx.x;

    // ---- stage + repack this edge's weights into LDS (0.5 folded) ----
    const float* Wg = W + (size_t)(2 * e) * (NCO * CIN * KW);  // 1536 contiguous floats
    #pragma unroll
    for (int it = 0; it < 6; ++it) {
        int f  = tid + it * BLOCK;            // 0..1535
        int j  = f / 768;  int r  = f - j * 768;
        int co = r / 48;   int r2 = r - co * 48;
        int ci = r2 / 3;   int k  = r2 - ci * 3;
        wlds[((j * 16 + ci) * 16 + co) * 4 + k] = 0.5f * Wg[f];
    }
    if (tid < NCO)
        blds[tid] = 0.5f * (b[(2 * e) * NCO + tid] + b[(2 * e + 1) * NCO + tid]);
    __syncthreads();

    const int cob = (tid >> 7) * COPT;     // 0 or 8; uniform per wave
    const int tg  = tid & (TGRP - 1);
    const int t0  = blockIdx.x * CHUNK + tg * TPT;   // multiple of 4 -> 16B aligned

    // float4 at t0 is always in-bounds (t0 <= 65532, +3 <= 65535).
    // float2 at t0+4 needs t0+5 <= 65535; else load a safe dummy (values unused).
    const bool safe2 = (t0 <= LSEQ - 6);
    const int  off2  = safe2 ? (t0 + 4) : t0;

    float acc[COPT][TPT];
    #pragma unroll
    for (int co = 0; co < COPT; ++co) {
        float bv = blds[cob + co];
        #pragma unroll
        for (int tt = 0; tt < TPT; ++tt) acc[co][tt] = bv;
    }

    const float4* wv = reinterpret_cast<const float4*>(wlds);

    #pragma unroll 1
    for (int ci = 0; ci < CIN; ++ci) {
        #pragma unroll
        for (int j = 0; j < 2; ++j) {
            const float* xp = x + (size_t)(ci * NJ + e + j) * LSEQ;
            const float4 v4 = *reinterpret_cast<const float4*>(xp + t0);
            const float2 v2 = *reinterpret_cast<const float2*>(xp + off2);
            float xv[6] = {v4.x, v4.y, v4.z, v4.w, v2.x, v2.y};
            #pragma unroll
            for (int co = 0; co < COPT; ++co) {
                const float4 w = wv[(j * 16 + ci) * 16 + cob + co];  // wave-uniform -> broadcast
                #pragma unroll
                for (int tt = 0; tt < TPT; ++tt) {
                    acc[co][tt] = fmaf(w.x, xv[tt],     acc[co][tt]);
                    acc[co][tt] = fmaf(w.y, xv[tt + 1], acc[co][tt]);
                    acc[co][tt] = fmaf(w.z, xv[tt + 2], acc[co][tt]);
                }
            }
        }
    }

    // ---- store: out[co, e, t] (rows only 4B-aligned -> dword stores) ----
    #pragma unroll
    for (int co = 0; co < COPT; ++co) {
        float* op = out + (size_t)((cob + co) * NE + e) * LOUTN;
        #pragma unroll
        for (int tt = 0; tt < TPT; ++tt) {
            int t = t0 + tt;
            if (t < LOUTN) op[t] = acc[co][tt];
        }
    }
}

extern "C" void kernel_launch(void* const* d_in, const int* in_sizes, int n_in,
                              void* d_out, int out_size, void* d_ws, size_t ws_size,
                              hipStream_t stream)
{
    const float* x = (const float*)d_in[0];
    const float* W = (const float*)d_in[1];
    const float* b = (const float*)d_in[2];
    float* out     = (float*)d_out;

    dim3 grid(NCHUNK, NE);
    skel_conv_kernel<<<grid, BLOCK, 0, stream>>>(x, W, b, out);
}

// Round 3
// 77.953 us; speedup vs baseline: 8.6775x; 1.0908x over previous
//
#include <hip/hip_runtime.h>

// SkeletalConv: grouped Conv1d over skeleton edges, fused neighbor-mean.
// x: (16, 25, 65536) f32, W: (48, 16, 16, 3) f32, b: (48, 16) f32
// out: (16, 24, 65533) f32
// out[co,e,t] = 0.5*sum_{j,ci,k} W[2e+j,co,ci,k]*x[ci,e+j,t+k] + 0.5*(b[2e,co]+b[2e+1,co])
//
// Strategy: weights are wave-uniform -> keep them in SGPRs (scalar loads from a
// repacked buffer in d_ws), zero LDS. Each block: one (edge, co-half, 2048-t chunk).
// Each thread: 8 co x 8 consecutive t accumulators, double-buffered x prefetch.

#define CIN   16
#define NJ    25
#define LSEQ  65536
#define NE    24
#define NCO   16
#define KW    3
#define LOUTN (LSEQ - KW + 1)          // 65533
#define COPT  8
#define TPT   8
#define BLOCK 256
#define CHUNK (BLOCK * TPT)            // 2048
#define NCHUNK ((LOUTN + CHUNK - 1) / CHUNK)   // 32
#define NWREP (NE * 2 * 32 * 24)       // 36864 repacked weights
#define NBREP (NE * 2 * 8)             // 384 repacked biases

// Wr layout: [e][half][p=ci*2+j][co(8)][k(3)], 0.5 folded in.
// Br layout: [e][half][co(8)] = 0.5*(b[2e,co]+b[2e+1,co])
__global__ void repack_kernel(const float* __restrict__ W, const float* __restrict__ b,
                              float* __restrict__ Wr, float* __restrict__ Br)
{
    int idx = blockIdx.x * BLOCK + threadIdx.x;
    if (idx < NWREP) {
        int k = idx % 3;  int r = idx / 3;
        int co = r & 7;   r >>= 3;
        int p  = r & 31;  r >>= 5;
        int half = r & 1; int e = r >> 1;
        int ci = p >> 1, j = p & 1;
        Wr[idx] = 0.5f * W[((2 * e + j) * 16 + half * 8 + co) * 48 + ci * 3 + k];
    }
    if (idx < NBREP) {
        int co8 = idx & 7; int r = idx >> 3;
        int half = r & 1;  int e = r >> 1;
        int co = half * 8 + co8;
        Br[idx] = 0.5f * (b[2 * e * 16 + co] + b[(2 * e + 1) * 16 + co]);
    }
}

__global__ __launch_bounds__(BLOCK)
void skel_conv_kernel(const float* __restrict__ x,
                      const float* __restrict__ Wr,
                      const float* __restrict__ Br,
                      float* __restrict__ out)
{
    const int e    = blockIdx.y;
    const int half = blockIdx.z;                       // uniform -> scalar weight addressing
    const int t0   = blockIdx.x * CHUNK + threadIdx.x * TPT;  // 32B-aligned

    // x loads cover t0..t0+9; last float2 may poke past LSEQ on the final lane
    // of the final chunk -> clamp (garbage only feeds invalid outputs).
    const bool safe2 = (t0 + TPT + 1 <= LSEQ - 1);
    const int  o2    = safe2 ? (t0 + 8) : t0;

    const float* wbase = Wr + (size_t)((e * 2 + half) * 32) * 24;
    const float* bb    = Br + (e * 2 + half) * 8;

    float acc[COPT][TPT];
    #pragma unroll
    for (int co = 0; co < COPT; ++co) {
        float bv = bb[co];
        #pragma unroll
        for (int tt = 0; tt < TPT; ++tt) acc[co][tt] = bv;
    }

    float A[TPT + 2], B[TPT + 2];

    auto loadx = [&](float* buf, int p) {
        const float* xp = x + (size_t)((p >> 1) * NJ + e + (p & 1)) * LSEQ;
        float4 a = *reinterpret_cast<const float4*>(xp + t0);
        float4 c = *reinterpret_cast<const float4*>(xp + t0 + 4);
        float2 d = *reinterpret_cast<const float2*>(xp + o2);
        buf[0] = a.x; buf[1] = a.y; buf[2] = a.z; buf[3] = a.w;
        buf[4] = c.x; buf[5] = c.y; buf[6] = c.z; buf[7] = c.w;
        buf[8] = d.x; buf[9] = d.y;
    };

    auto body = [&](const float* buf, int p) {
        const float* wp = wbase + p * 24;              // uniform -> s_load
        #pragma unroll
        for (int co = 0; co < COPT; ++co) {
            float w0 = wp[co * 3 + 0];
            float w1 = wp[co * 3 + 1];
            float w2 = wp[co * 3 + 2];
            #pragma unroll
            for (int tt = 0; tt < TPT; ++tt) {
                acc[co][tt] = fmaf(w0, buf[tt],     acc[co][tt]);
                acc[co][tt] = fmaf(w1, buf[tt + 1], acc[co][tt]);
                acc[co][tt] = fmaf(w2, buf[tt + 2], acc[co][tt]);
            }
        }
    };

    loadx(A, 0);
    #pragma unroll 1
    for (int p = 0; p < 32; p += 2) {
        loadx(B, p + 1);
        body(A, p);
        if (p + 2 < 32) loadx(A, p + 2);
        body(B, p + 1);
    }

    // ---- store: out[co_global, e, t] ----
    const bool full = (t0 + TPT <= LOUTN);
    #pragma unroll
    for (int co = 0; co < COPT; ++co) {
        float* op = out + (size_t)((half * 8 + co) * NE + e) * LOUTN + t0;
        if (full) {
            #pragma unroll
            for (int tt = 0; tt < TPT; ++tt) op[tt] = acc[co][tt];
        } else {
            #pragma unroll
            for (int tt = 0; tt < TPT; ++tt)
                if (t0 + tt < LOUTN) op[tt] = acc[co][tt];
        }
    }
}

extern "C" void kernel_launch(void* const* d_in, const int* in_sizes, int n_in,
                              void* d_out, int out_size, void* d_ws, size_t ws_size,
                              hipStream_t stream)
{
    const float* x = (const float*)d_in[0];
    const float* W = (const float*)d_in[1];
    const float* b = (const float*)d_in[2];
    float* out     = (float*)d_out;

    float* Wr = (float*)d_ws;            // 36864 floats
    float* Br = Wr + NWREP;              // 384 floats (total ~149 KB of d_ws)

    repack_kernel<<<(NWREP + BLOCK - 1) / BLOCK, BLOCK, 0, stream>>>(W, b, Wr, Br);

    dim3 grid(NCHUNK, NE, 2);
    skel_conv_kernel<<<grid, BLOCK, 0, stream>>>(x, Wr, Br, out);
}